// Round 12
// baseline (295.593 us; speedup 1.0000x reference)
//
#include <hip/hip_runtime.h>

// LightGCN propagation, CSR-gather, bf16 intermediates, unified row space.
// R21 (from R20 @272.8us; best = R18 @267.2):
//  - Heterogeneous CSR+convert fusion is sum-not-max at every granularity
//    (R18/R20); drop it. The only worthwhile overlap: scatter || convert.
//  - R19 showed they co-schedule but convert's L2 traffic evicted partial
//    partBuf lines (WRITE 64->95MB). Fix: convert uses NONTEMPORAL loads
//    and stores (full-line streaming, the textbook NT case) so it bypasses
//    L2 and partBuf keeps L2 residency for line merging.
//  - Pipeline: memset -> prep -> front{scatter || NT-convert} ->
//    csr@1024 || compact -> agg1 -> agg2+add1 -> aggout.

#define N_USERS 200000
#define N_ITEMS 100000
#define N_EDGES 1000000
#define DIM 64
#define BATCH 8192
#define NTOT (N_USERS + N_ITEMS)          // 300000 rows
#define NOUT (3 * BATCH)                  // 24576 output rows
#define NPART 293                         // ceil(NTOT / 1024)
#define PLOCAL 1024
#define CAP 11264                         // per-partition record capacity

#define HA 489                            // scatter blocks: 8 edges/thread
#define NUNITS (NTOT * DIM / 8)           // 2.4M 8-float convert units
#define CB ((NUNITS + 1023) / 1024)       // 2344 convert blocks (32 floats/thread, 256thr)
#define OB (NOUT * 8 / 256)               // 768 add1 blocks (8 floats/thread)
#define AB8 (NTOT / 32)                   // 9375 agg blocks (32 rows/block)
#define PRB (NOUT / 1024)                 // 24 isOut blocks (1024 thr)
#define PHB (NOUT * 8 / 1024)             // 192 out_h0 blocks (1024 thr)
#define CPB ((NTOT / 4 + 1023) / 1024)    // 74 compact blocks (1024 thr)

// ext-vector types for nontemporal builtins
typedef float    floatx4 __attribute__((ext_vector_type(4)));
typedef unsigned uint4v  __attribute__((ext_vector_type(4)));

// ---------- bf16 helpers ----------
__device__ __forceinline__ unsigned f2bf(float f) {   // round-to-nearest-even
    unsigned u = __float_as_uint(f);
    return (u + 0x7fffu + ((u >> 16) & 1u)) >> 16;
}
__device__ __forceinline__ uint2 pack4(float4 v) {
    uint2 o;
    o.x = f2bf(v.x) | (f2bf(v.y) << 16);
    o.y = f2bf(v.z) | (f2bf(v.w) << 16);
    return o;
}
__device__ __forceinline__ uint2 pack4v(floatx4 v) {
    uint2 o;
    o.x = f2bf(v[0]) | (f2bf(v[1]) << 16);
    o.y = f2bf(v[2]) | (f2bf(v[3]) << 16);
    return o;
}
__device__ __forceinline__ void fma4(float4& a, uint2 v, float w) {
    a.x += __uint_as_float(v.x << 16) * w;
    a.y += __uint_as_float(v.x & 0xffff0000u) * w;
    a.z += __uint_as_float(v.y << 16) * w;
    a.w += __uint_as_float(v.y & 0xffff0000u) * w;
}
__device__ __forceinline__ int out_bucket(int orow, const int* users,
                                          const int* pos, const int* neg) {
    int seg = orow >> 13;
    int b = orow & (BATCH - 1);
    if (seg == 0) return users[b];
    if (seg == 1) return N_USERS + pos[b];
    return N_USERS + neg[b];
}

// ---------------- P: isOut bitmap + flags[bucket] + out_h0 ----------------
__global__ void __launch_bounds__(1024)
prep_kernel(const int* __restrict__ users,
            const int* __restrict__ pos,
            const int* __restrict__ neg,
            const float* __restrict__ u_feat,
            const float* __restrict__ i_feat,
            unsigned char* __restrict__ isOut,
            int* __restrict__ flags,
            float* __restrict__ out)
{
    int bid = blockIdx.x, t = threadIdx.x;
    if (bid < PRB) {
        int orow = bid * 1024 + t;                   // [0, NOUT) exactly
        int bucket = out_bucket(orow, users, pos, neg);
        isOut[bucket] = 1;
        flags[bucket] = 1;
    } else {
        // out = 0.25 * h0 at gathered rows, 8 floats/thread
        int idx = (bid - PRB) * 1024 + t;            // [0, NOUT*8) exactly
        int row = idx >> 3;
        int d8 = (idx & 7) << 3;
        int seg = row >> 13;
        int b = row & (BATCH - 1);
        const float* src;
        if (seg == 0)      src = u_feat + (size_t)users[b] * DIM;
        else if (seg == 1) src = i_feat + (size_t)pos[b]   * DIM;
        else               src = i_feat + (size_t)neg[b]   * DIM;
        float4 v0 = *reinterpret_cast<const float4*>(src + d8);
        float4 v1 = *reinterpret_cast<const float4*>(src + d8 + 4);
        v0.x *= 0.25f; v0.y *= 0.25f; v0.z *= 0.25f; v0.w *= 0.25f;
        v1.x *= 0.25f; v1.y *= 0.25f; v1.z *= 0.25f; v1.w *= 0.25f;
        float* op = out + (size_t)row * DIM + d8;
        *reinterpret_cast<float4*>(op) = v0;
        *reinterpret_cast<float4*>(op + 4) = v1;
    }
}

// ---------------- F: scatter || NT-convert (one 256-thr launch) ----------------
// record meta = (bucket & 1023) | (col << 10);  col < 2^19, total 29 bits.
// gcur[p] is ZERO-based (memset); record address = p*CAP + cursor.
// Convert uses NONTEMPORAL loads+stores (full-line streaming) so it does NOT
// occupy L2 — partBuf lines stay resident and merge before writeback.
__global__ void __launch_bounds__(256)
front_kernel(const int* __restrict__ eu,
             const int* __restrict__ ei,
             const float* __restrict__ w,
             int* __restrict__ gcur,
             uint2* __restrict__ partBuf,
             const unsigned char* __restrict__ isOut,
             int* __restrict__ flags,
             const floatx4* __restrict__ uf4,
             const floatx4* __restrict__ if4,
             unsigned short* __restrict__ F0)
{
    int bid = blockIdx.x, t = threadIdx.x;
    if (bid < HA) {
        __shared__ int lh[NPART];
        __shared__ int lcur[NPART];
        for (int k = t; k < NPART; k += 256) lh[k] = 0;
        __syncthreads();
        int e0 = (bid * 256 + t) * 8;
        bool act = e0 < N_EDGES;
        int4 u0, u1, i0, i1;
        if (act) {
            u0 = *reinterpret_cast<const int4*>(eu + e0);
            u1 = *reinterpret_cast<const int4*>(eu + e0 + 4);
            i0 = *reinterpret_cast<const int4*>(ei + e0);
            i1 = *reinterpret_cast<const int4*>(ei + e0 + 4);
            atomicAdd(&lh[u0.x >> 10], 1);
            atomicAdd(&lh[u0.y >> 10], 1);
            atomicAdd(&lh[u0.z >> 10], 1);
            atomicAdd(&lh[u0.w >> 10], 1);
            atomicAdd(&lh[u1.x >> 10], 1);
            atomicAdd(&lh[u1.y >> 10], 1);
            atomicAdd(&lh[u1.z >> 10], 1);
            atomicAdd(&lh[u1.w >> 10], 1);
            atomicAdd(&lh[(N_USERS + i0.x) >> 10], 1);
            atomicAdd(&lh[(N_USERS + i0.y) >> 10], 1);
            atomicAdd(&lh[(N_USERS + i0.z) >> 10], 1);
            atomicAdd(&lh[(N_USERS + i0.w) >> 10], 1);
            atomicAdd(&lh[(N_USERS + i1.x) >> 10], 1);
            atomicAdd(&lh[(N_USERS + i1.y) >> 10], 1);
            atomicAdd(&lh[(N_USERS + i1.z) >> 10], 1);
            atomicAdd(&lh[(N_USERS + i1.w) >> 10], 1);
        }
        __syncthreads();
        // reserve: one returning atomic per (block, nonempty partition)
        for (int k = t; k < NPART; k += 256) {
            int v = lh[k];
            lcur[k] = v ? atomicAdd(&gcur[k], v) : 0;
        }
        __syncthreads();
        if (act) {
            float4 wa = *reinterpret_cast<const float4*>(w + e0);
            float4 wb = *reinterpret_cast<const float4*>(w + e0 + 4);
            int us[8] = {u0.x, u0.y, u0.z, u0.w, u1.x, u1.y, u1.z, u1.w};
            int is[8] = {i0.x, i0.y, i0.z, i0.w, i1.x, i1.y, i1.z, i1.w};
            float ws[8] = {wa.x, wa.y, wa.z, wa.w, wb.x, wb.y, wb.z, wb.w};
            #pragma unroll
            for (int j = 0; j < 8; ++j) {
                int bu = us[j];
                int bi = N_USERS + is[j];
                unsigned wbits = __float_as_uint(ws[j]);
                int pu = bu >> 10, pi = bi >> 10;
                int su = atomicAdd(&lcur[pu], 1);      // LDS cursor
                partBuf[(size_t)pu * CAP + su] =
                    make_uint2((unsigned)(bu & 1023) | ((unsigned)bi << 10), wbits);
                int si = atomicAdd(&lcur[pi], 1);      // LDS cursor
                partBuf[(size_t)pi * CAP + si] =
                    make_uint2((unsigned)(bi & 1023) | ((unsigned)bu << 10), wbits);
                // flags for H2-needed rows, straight from the edge
                if (isOut[bu]) flags[bi] = 1;
                if (isOut[bi]) flags[bu] = 1;
            }
        }
    } else {
        // ---- NT f32 -> bf16 convert, 32 floats/thread, 8 loads in flight ----
        const int NU4 = N_USERS * DIM / 4;           // 3.2M float4s (user side)
        int jb = (bid - HA) * 1024 + t;              // 8-float unit index
        floatx4 a[4], b[4];
        #pragma unroll
        for (int c = 0; c < 4; ++c) {
            int j = jb + c * 256;
            if (j < NUNITS) {
                int f4 = j * 2;
                if (f4 < NU4) {
                    a[c] = __builtin_nontemporal_load(uf4 + f4);
                    b[c] = __builtin_nontemporal_load(uf4 + f4 + 1);
                } else {
                    a[c] = __builtin_nontemporal_load(if4 + (f4 - NU4));
                    b[c] = __builtin_nontemporal_load(if4 + (f4 - NU4) + 1);
                }
            }
        }
        #pragma unroll
        for (int c = 0; c < 4; ++c) {
            int j = jb + c * 256;
            if (j < NUNITS) {
                uint2 pa = pack4v(a[c]), pb = pack4v(b[c]);
                uint4v o = {pa.x, pa.y, pb.x, pb.y};
                __builtin_nontemporal_store(o, (uint4v*)(F0 + (size_t)j * 8));
            }
        }
    }
}

// ---------------- C: CSR(1024thr) || compact ----------------
__global__ void __launch_bounds__(1024)
csr_compact_kernel(const int* __restrict__ gcur,
                   const uint2* __restrict__ partBuf,
                   int2* __restrict__ rp2,
                   int2* __restrict__ entries,
                   const int* __restrict__ flags,
                   int* __restrict__ list,
                   int* __restrict__ count)
{
    int bid = blockIdx.x, t = threadIdx.x;
    if (bid < NPART) {
        __shared__ int h[PLOCAL];
        __shared__ int s[PLOCAL];
        __shared__ int cur[PLOCAL];
        int p = bid;
        int base = p * CAP;
        int end = base + gcur[p];
        h[t] = 0;
        __syncthreads();
        for (int r = base + t; r < end; r += 1024)
            atomicAdd(&h[partBuf[r].x & 1023], 1);
        __syncthreads();
        s[t] = h[t];
        __syncthreads();
        for (int off = 1; off < 1024; off <<= 1) {
            int x = (t >= off) ? s[t - off] : 0;
            __syncthreads();
            s[t] += x;
            __syncthreads();
        }
        int c0 = base + s[t] - h[t];    // exclusive scan -> bucket start (abs)
        cur[t] = c0;
        int gb = p * PLOCAL + t;
        if (gb < NTOT) rp2[gb] = make_int2(c0, h[t]);
        __syncthreads();
        for (int r = base + t; r < end; r += 1024) {
            uint2 rec = partBuf[r];
            int slot = atomicAdd(&cur[rec.x & 1023], 1);   // LDS
            entries[slot] = make_int2((int)(rec.x >> 10), (int)rec.y);
        }
    } else {
        // ---- compact flags -> row list ----
        int idx = ((bid - NPART) * 1024 + t) * 4;
        if (idx >= NTOT) return;
        int4 f = *reinterpret_cast<const int4*>(flags + idx);
        int loc[4]; int k = 0;
        if (f.x) loc[k++] = idx;
        if (f.y) loc[k++] = idx + 1;
        if (f.z) loc[k++] = idx + 2;
        if (f.w) loc[k++] = idx + 3;
        if (k) {
            int base = atomicAdd(count, k);
            for (int m = 0; m < k; ++m) list[base + m] = loc[m];
        }
    }
}

// ---------------- agg core: branchless masked rounds, 8 lanes/row ----------------
// rp2 = {beg,cnt} -> single dwordx2 at chain head. Masked slots: e={0,0} ->
// row 0, w=0.0 -> exact +0, L1-hot.
__device__ __forceinline__ void agg_row8(int2 rc, int l8, int gb,
                                         const int2* __restrict__ entries,
                                         const unsigned short* __restrict__ src,
                                         float4& sL, float4& sH)
{
    int beg = rc.x, cnt = rc.y;
    float4 a0L = {0,0,0,0}, a0H = {0,0,0,0}, a1L = {0,0,0,0}, a1H = {0,0,0,0};
    for (int base = 0; base < cnt; base += 8) {
        int2 e = make_int2(0, 0);
        if (base + l8 < cnt) e = entries[beg + base + l8];
        int   c[8];
        float wv[8];
        #pragma unroll
        for (int k = 0; k < 8; ++k) {
            c[k]  = __shfl(e.x, gb + k);
            wv[k] = __int_as_float(__shfl(e.y, gb + k));
        }
        uint4 v[8];
        #pragma unroll
        for (int k = 0; k < 8; ++k)
            v[k] = *reinterpret_cast<const uint4*>(
                src + (size_t)c[k] * DIM + l8 * 8);
        #pragma unroll
        for (int k = 0; k < 8; ++k) {
            if (k & 1) {
                fma4(a1L, make_uint2(v[k].x, v[k].y), wv[k]);
                fma4(a1H, make_uint2(v[k].z, v[k].w), wv[k]);
            } else {
                fma4(a0L, make_uint2(v[k].x, v[k].y), wv[k]);
                fma4(a0H, make_uint2(v[k].z, v[k].w), wv[k]);
            }
        }
    }
    sL.x = a0L.x + a1L.x; sL.y = a0L.y + a1L.y;
    sL.z = a0L.z + a1L.z; sL.w = a0L.w + a1L.w;
    sH.x = a0H.x + a1H.x; sH.y = a0H.y + a1H.y;
    sH.z = a0H.z + a1H.z; sH.w = a0H.w + a1H.w;
}

// ---------------- layer 1 (all rows, gather only) ----------------
__global__ void agg1_kernel(const int2* __restrict__ rp2,
                            const int2* __restrict__ entries,
                            const unsigned short* __restrict__ F0,
                            unsigned short* __restrict__ H1)
{
    int gid = blockIdx.x * 256 + threadIdx.x;
    int lane = gid & 63;
    int l8 = lane & 7;
    int gb = lane & 56;
    int row = gid >> 3;
    if (row >= NTOT) return;
    float4 sL, sH;
    agg_row8(rp2[row], l8, gb, entries, F0, sL, sH);
    uint2 pL = pack4(sL), pH = pack4(sH);
    *reinterpret_cast<uint4*>(H1 + (size_t)row * DIM + l8 * 8) =
        make_uint4(pL.x, pL.y, pH.x, pH.y);
}

// ---------------- layer 2 (listed rows only) + out += 0.25*H1 ----------------
__global__ void agg2_add1_kernel(const int2* __restrict__ rp2,
                                 const int2* __restrict__ entries,
                                 const unsigned short* __restrict__ H1,
                                 unsigned short* __restrict__ H2,
                                 const int* __restrict__ list,
                                 const int* __restrict__ count,
                                 const int* __restrict__ users,
                                 const int* __restrict__ pos,
                                 const int* __restrict__ neg,
                                 float* __restrict__ out)
{
    int bid = blockIdx.x;
    if (bid < AB8) {
        int gid = bid * 256 + threadIdx.x;
        int lane = gid & 63;
        int l8 = lane & 7;
        int gb = lane & 56;
        int idx = gid >> 3;
        int n = *count;
        if (idx >= n) return;
        int row = list[idx];
        float4 sL, sH;
        agg_row8(rp2[row], l8, gb, entries, H1, sL, sH);
        uint2 pL = pack4(sL), pH = pack4(sH);
        *reinterpret_cast<uint4*>(H2 + (size_t)row * DIM + l8 * 8) =
            make_uint4(pL.x, pL.y, pH.x, pH.y);
    } else {
        // out += 0.25 * H1[bucket], 8 floats/thread (matches OB = NOUT*8/256)
        int idx = (bid - AB8) * 256 + threadIdx.x;   // [0, NOUT*8)
        int row = idx >> 3;
        if (row >= NOUT) return;
        int d8 = (idx & 7) << 3;
        int bucket = out_bucket(row, users, pos, neg);
        uint4 v = *reinterpret_cast<const uint4*>(H1 + (size_t)bucket * DIM + d8);
        float* op = out + (size_t)row * DIM + d8;
        float4 o0 = *reinterpret_cast<const float4*>(op);
        float4 o1 = *reinterpret_cast<const float4*>(op + 4);
        o0.x += 0.25f * __uint_as_float(v.x << 16);
        o0.y += 0.25f * __uint_as_float(v.x & 0xffff0000u);
        o0.z += 0.25f * __uint_as_float(v.y << 16);
        o0.w += 0.25f * __uint_as_float(v.y & 0xffff0000u);
        o1.x += 0.25f * __uint_as_float(v.z << 16);
        o1.y += 0.25f * __uint_as_float(v.z & 0xffff0000u);
        o1.z += 0.25f * __uint_as_float(v.w << 16);
        o1.w += 0.25f * __uint_as_float(v.w & 0xffff0000u);
        *reinterpret_cast<float4*>(op) = o0;
        *reinterpret_cast<float4*>(op + 4) = o1;
    }
}

// ---------------- layer 3 at output rows, H2 add fused IN-THREAD ----------------
__global__ void aggout_add2_kernel(const int2* __restrict__ rp2,
                                   const int2* __restrict__ entries,
                                   const unsigned short* __restrict__ H2,
                                   const int* __restrict__ users,
                                   const int* __restrict__ pos,
                                   const int* __restrict__ neg,
                                   float* __restrict__ out)
{
    int gid = blockIdx.x * 256 + threadIdx.x;
    int lane = gid & 63;
    int l8 = lane & 7;
    int gb = lane & 56;
    int orow = gid >> 3;
    if (orow >= NOUT) return;
    int bucket = out_bucket(orow, users, pos, neg);
    float4 sL, sH;
    agg_row8(rp2[bucket], l8, gb, entries, H2, sL, sH);
    uint4 v = *reinterpret_cast<const uint4*>(H2 + (size_t)bucket * DIM + l8 * 8);
    sL.x += __uint_as_float(v.x << 16);
    sL.y += __uint_as_float(v.x & 0xffff0000u);
    sL.z += __uint_as_float(v.y << 16);
    sL.w += __uint_as_float(v.y & 0xffff0000u);
    sH.x += __uint_as_float(v.z << 16);
    sH.y += __uint_as_float(v.z & 0xffff0000u);
    sH.z += __uint_as_float(v.w << 16);
    sH.w += __uint_as_float(v.w & 0xffff0000u);
    float* op = out + (size_t)orow * DIM + l8 * 8;
    float4 o0 = *reinterpret_cast<const float4*>(op);
    float4 o1 = *reinterpret_cast<const float4*>(op + 4);
    o0.x += 0.25f * sL.x; o0.y += 0.25f * sL.y;
    o0.z += 0.25f * sL.z; o0.w += 0.25f * sL.w;
    o1.x += 0.25f * sH.x; o1.y += 0.25f * sH.y;
    o1.z += 0.25f * sH.z; o1.w += 0.25f * sH.w;
    *reinterpret_cast<float4*>(op) = o0;
    *reinterpret_cast<float4*>(op + 4) = o1;
}

extern "C" void kernel_launch(void* const* d_in, const int* in_sizes, int n_in,
                              void* d_out, int out_size, void* d_ws, size_t ws_size,
                              hipStream_t stream)
{
    const float* user_feat = (const float*)d_in[0];
    const float* item_feat = (const float*)d_in[1];
    const int*   eu        = (const int*)d_in[2];
    const int*   ei        = (const int*)d_in[3];
    const float* norm      = (const float*)d_in[4];
    const int*   users     = (const int*)d_in[5];
    const int*   pos       = (const int*)d_in[6];
    const int*   neg       = (const int*)d_in[7];
    float* out = (float*)d_out;

    auto align256 = [](size_t x) { return (x + 255) & ~(size_t)255; };
    const size_t hBytes = (size_t)NTOT * DIM * sizeof(unsigned short);  // 38.4 MB
    const size_t pBytes = (size_t)NPART * CAP * 8;                      // 26.4 MB

    char* p = (char*)d_ws;
    unsigned short* F0 = (unsigned short*)p; p += align256(hBytes);
    unsigned short* H1 = (unsigned short*)p; p += align256(hBytes);
    unsigned short* H2 = (unsigned short*)p; p += align256(hBytes);
    // memset region: gcur(512 pad) | flags(NTOT) | count(16 pad) | isOut(NTOT B)
    const size_t zBytes = (size_t)(512 + NTOT + 16) * 4 + NTOT;
    int* gcur = (int*)p;
    int* flags = gcur + 512;
    int* count = flags + NTOT;
    unsigned char* isOut = (unsigned char*)(count + 16);
    p += align256(zBytes);
    int2* rp2      = (int2*)p;  p += align256((size_t)NTOT * 8);
    uint2* partBuf = (uint2*)p; p += align256(pBytes);
    int*  list     = (int*)p;   p += align256((size_t)NTOT * 4);
    int2* entries  = (int2*)p;  p += align256(pBytes);
    // total ~175 MB

    hipMemsetAsync(gcur, 0, zBytes, stream);

    // P: isOut bitmap + flags[bucket] + out_h0
    prep_kernel<<<PRB + PHB, 1024, 0, stream>>>(
        users, pos, neg, user_feat, item_feat, isOut, flags, out);

    // F: scatter || NT-convert (convert bypasses L2; partBuf keeps residency)
    front_kernel<<<HA + CB, 256, 0, stream>>>(
        eu, ei, norm, gcur, partBuf, isOut, flags,
        (const floatx4*)user_feat, (const floatx4*)item_feat, F0);

    // C: CSR(1024thr) || compact
    csr_compact_kernel<<<NPART + CPB, 1024, 0, stream>>>(
        gcur, partBuf, rp2, entries, flags, list, count);

    // layer 1 (all rows, gather only)
    agg1_kernel<<<AB8, 256, 0, stream>>>(rp2, entries, F0, H1);

    // layer 2 (listed rows) + out += 0.25*H1
    agg2_add1_kernel<<<AB8 + OB, 256, 0, stream>>>(
        rp2, entries, H1, H2, list, count, users, pos, neg, out);

    // layer 3 at output rows with in-thread H2 add
    aggout_add2_kernel<<<NOUT / 32, 256, 0, stream>>>(
        rp2, entries, H2, users, pos, neg, out);
}

// Round 13
// 268.320 us; speedup vs baseline: 1.1016x; 1.1016x over previous
//
#include <hip/hip_runtime.h>

// LightGCN propagation, CSR-gather, bf16 intermediates, unified row space.
// R22 (= R18 @267.2us + wave-scan CSR; R19/R20/R21 overlap attempts all
// regressed and are abandoned):
//  - Verdict table: scatter must run ALONE (concurrent streams amplify
//    partBuf partial-line writebacks: R19 95MB, R21 NT didn't help);
//    CSR+convert co-launch is sum-not-max but still the best mid (R18).
//  - This round: mid's CSR prefix scan 20 barriers -> 2 barriers via
//    per-wave __shfl_up scan + wave-sum scan by wave 0.
//  - Everything else byte-identical to R18.

#define N_USERS 200000
#define N_ITEMS 100000
#define N_EDGES 1000000
#define DIM 64
#define BATCH 8192
#define NTOT (N_USERS + N_ITEMS)          // 300000 rows
#define NOUT (3 * BATCH)                  // 24576 output rows
#define NPART 293                         // ceil(NTOT / 1024)
#define PLOCAL 1024
#define CAP 11264                         // per-partition record capacity

#define HA 489                            // scatter blocks: 8 edges/thread
#define NUNITS (NTOT * DIM / 8)           // 2.4M 8-float convert units
#define OB (NOUT * 8 / 256)               // 768 add1 blocks (8 floats/thread)
#define AB8 (NTOT / 32)                   // 9375 agg blocks (32 rows/block)
#define PRB (NOUT / 1024)                 // 24 isOut blocks (1024 thr)
#define PHB (NOUT * 8 / 1024)             // 192 out_h0 blocks (1024 thr)
#define CVB ((NUNITS + 4095) / 4096)      // 586 convert blocks (32 floats/thread, 1024thr)
#define CPB ((NTOT / 4 + 1023) / 1024)    // 74 compact blocks (1024 thr)

// ---------- bf16 helpers ----------
__device__ __forceinline__ unsigned f2bf(float f) {   // round-to-nearest-even
    unsigned u = __float_as_uint(f);
    return (u + 0x7fffu + ((u >> 16) & 1u)) >> 16;
}
__device__ __forceinline__ uint2 pack4(float4 v) {
    uint2 o;
    o.x = f2bf(v.x) | (f2bf(v.y) << 16);
    o.y = f2bf(v.z) | (f2bf(v.w) << 16);
    return o;
}
__device__ __forceinline__ void fma4(float4& a, uint2 v, float w) {
    a.x += __uint_as_float(v.x << 16) * w;
    a.y += __uint_as_float(v.x & 0xffff0000u) * w;
    a.z += __uint_as_float(v.y << 16) * w;
    a.w += __uint_as_float(v.y & 0xffff0000u) * w;
}
__device__ __forceinline__ int out_bucket(int orow, const int* users,
                                          const int* pos, const int* neg) {
    int seg = orow >> 13;
    int b = orow & (BATCH - 1);
    if (seg == 0) return users[b];
    if (seg == 1) return N_USERS + pos[b];
    return N_USERS + neg[b];
}

// ---------------- P: isOut bitmap + flags[bucket] + out_h0 ----------------
__global__ void __launch_bounds__(1024)
prep_kernel(const int* __restrict__ users,
            const int* __restrict__ pos,
            const int* __restrict__ neg,
            const float* __restrict__ u_feat,
            const float* __restrict__ i_feat,
            unsigned char* __restrict__ isOut,
            int* __restrict__ flags,
            float* __restrict__ out)
{
    int bid = blockIdx.x, t = threadIdx.x;
    if (bid < PRB) {
        int orow = bid * 1024 + t;                   // [0, NOUT) exactly
        int bucket = out_bucket(orow, users, pos, neg);
        isOut[bucket] = 1;
        flags[bucket] = 1;
    } else {
        // out = 0.25 * h0 at gathered rows, 8 floats/thread
        int idx = (bid - PRB) * 1024 + t;            // [0, NOUT*8) exactly
        int row = idx >> 3;
        int d8 = (idx & 7) << 3;
        int seg = row >> 13;
        int b = row & (BATCH - 1);
        const float* src;
        if (seg == 0)      src = u_feat + (size_t)users[b] * DIM;
        else if (seg == 1) src = i_feat + (size_t)pos[b]   * DIM;
        else               src = i_feat + (size_t)neg[b]   * DIM;
        float4 v0 = *reinterpret_cast<const float4*>(src + d8);
        float4 v1 = *reinterpret_cast<const float4*>(src + d8 + 4);
        v0.x *= 0.25f; v0.y *= 0.25f; v0.z *= 0.25f; v0.w *= 0.25f;
        v1.x *= 0.25f; v1.y *= 0.25f; v1.z *= 0.25f; v1.w *= 0.25f;
        float* op = out + (size_t)row * DIM + d8;
        *reinterpret_cast<float4*>(op) = v0;
        *reinterpret_cast<float4*>(op + 4) = v1;
    }
}

// ---------------- B: partition scatter + edge-based flags (ALONE) ----------------
// record meta = (bucket & 1023) | (col << 10);  col < 2^19, total 29 bits.
// gcur[p] is ZERO-based (memset); record address = p*CAP + cursor.
__global__ void __launch_bounds__(256)
scatter_kernel(const int* __restrict__ eu,
               const int* __restrict__ ei,
               const float* __restrict__ w,
               int* __restrict__ gcur,
               uint2* __restrict__ partBuf,
               const unsigned char* __restrict__ isOut,
               int* __restrict__ flags)
{
    __shared__ int lh[NPART];
    __shared__ int lcur[NPART];
    int bid = blockIdx.x, t = threadIdx.x;
    for (int k = t; k < NPART; k += 256) lh[k] = 0;
    __syncthreads();
    int e0 = (bid * 256 + t) * 8;
    bool act = e0 < N_EDGES;
    int4 u0, u1, i0, i1;
    if (act) {
        u0 = *reinterpret_cast<const int4*>(eu + e0);
        u1 = *reinterpret_cast<const int4*>(eu + e0 + 4);
        i0 = *reinterpret_cast<const int4*>(ei + e0);
        i1 = *reinterpret_cast<const int4*>(ei + e0 + 4);
        atomicAdd(&lh[u0.x >> 10], 1);
        atomicAdd(&lh[u0.y >> 10], 1);
        atomicAdd(&lh[u0.z >> 10], 1);
        atomicAdd(&lh[u0.w >> 10], 1);
        atomicAdd(&lh[u1.x >> 10], 1);
        atomicAdd(&lh[u1.y >> 10], 1);
        atomicAdd(&lh[u1.z >> 10], 1);
        atomicAdd(&lh[u1.w >> 10], 1);
        atomicAdd(&lh[(N_USERS + i0.x) >> 10], 1);
        atomicAdd(&lh[(N_USERS + i0.y) >> 10], 1);
        atomicAdd(&lh[(N_USERS + i0.z) >> 10], 1);
        atomicAdd(&lh[(N_USERS + i0.w) >> 10], 1);
        atomicAdd(&lh[(N_USERS + i1.x) >> 10], 1);
        atomicAdd(&lh[(N_USERS + i1.y) >> 10], 1);
        atomicAdd(&lh[(N_USERS + i1.z) >> 10], 1);
        atomicAdd(&lh[(N_USERS + i1.w) >> 10], 1);
    }
    __syncthreads();
    // reserve: one returning atomic per (block, nonempty partition)
    for (int k = t; k < NPART; k += 256) {
        int v = lh[k];
        lcur[k] = v ? atomicAdd(&gcur[k], v) : 0;
    }
    __syncthreads();
    if (act) {
        float4 wa = *reinterpret_cast<const float4*>(w + e0);
        float4 wb = *reinterpret_cast<const float4*>(w + e0 + 4);
        int us[8] = {u0.x, u0.y, u0.z, u0.w, u1.x, u1.y, u1.z, u1.w};
        int is[8] = {i0.x, i0.y, i0.z, i0.w, i1.x, i1.y, i1.z, i1.w};
        float ws[8] = {wa.x, wa.y, wa.z, wa.w, wb.x, wb.y, wb.z, wb.w};
        #pragma unroll
        for (int j = 0; j < 8; ++j) {
            int bu = us[j];
            int bi = N_USERS + is[j];
            unsigned wbits = __float_as_uint(ws[j]);
            int pu = bu >> 10, pi = bi >> 10;
            int su = atomicAdd(&lcur[pu], 1);      // LDS cursor
            partBuf[(size_t)pu * CAP + su] =
                make_uint2((unsigned)(bu & 1023) | ((unsigned)bi << 10), wbits);
            int si = atomicAdd(&lcur[pi], 1);      // LDS cursor
            partBuf[(size_t)pi * CAP + si] =
                make_uint2((unsigned)(bi & 1023) | ((unsigned)bu << 10), wbits);
            // flags for H2-needed rows, straight from the edge
            if (isOut[bu]) flags[bi] = 1;
            if (isOut[bi]) flags[bu] = 1;
        }
    }
}

// ---------------- M: csr | convert | compact (one wide 1024-thr launch) ----------------
__global__ void __launch_bounds__(1024)
mid_kernel(const int* __restrict__ gcur,
           const uint2* __restrict__ partBuf,
           int2* __restrict__ rp2,
           int2* __restrict__ entries,
           const float4* __restrict__ uf4,
           const float4* __restrict__ if4,
           unsigned short* __restrict__ F0,
           const int* __restrict__ flags,
           int* __restrict__ list,
           int* __restrict__ count)
{
    int bid = blockIdx.x, t = threadIdx.x;
    if (bid < NPART) {
        // ---- per-partition CSR build, wave-scan (2 barriers, was 20) ----
        __shared__ int h[PLOCAL];
        __shared__ int cur[PLOCAL];
        __shared__ int wsum[16];
        int p = bid;
        int base = p * CAP;
        int end = base + gcur[p];
        h[t] = 0;
        __syncthreads();
        for (int r = base + t; r < end; r += 1024)
            atomicAdd(&h[partBuf[r].x & 1023], 1);
        __syncthreads();
        int v = h[t];
        // per-wave inclusive scan (64 lanes, no barrier)
        int s = v;
        #pragma unroll
        for (int off = 1; off < 64; off <<= 1) {
            int x = __shfl_up(s, off, 64);
            if ((t & 63) >= off) s += x;
        }
        if ((t & 63) == 63) wsum[t >> 6] = s;
        __syncthreads();
        if (t < 16) {
            int ws = wsum[t];
            int acc = ws;
            #pragma unroll
            for (int off = 1; off < 16; off <<= 1) {
                int x = __shfl_up(acc, off, 64);
                if (t >= off) acc += x;
            }
            wsum[t] = acc - ws;                      // exclusive wave offset
        }
        __syncthreads();
        int excl = (s - v) + wsum[t >> 6];           // exclusive prefix over block
        int c0 = base + excl;
        cur[t] = c0;
        int gb = p * PLOCAL + t;
        if (gb < NTOT) rp2[gb] = make_int2(c0, v);
        __syncthreads();
        for (int r = base + t; r < end; r += 1024) {
            uint2 rec = partBuf[r];
            int slot = atomicAdd(&cur[rec.x & 1023], 1);   // LDS
            entries[slot] = make_int2((int)(rec.x >> 10), (int)rec.y);
        }
    } else if (bid < NPART + CVB) {
        // ---- f32 -> bf16 convert, 32 floats/thread, 8 loads in flight ----
        const int NU4 = N_USERS * DIM / 4;           // 3.2M float4s (user side)
        int jb = (bid - NPART) * 4096 + t;           // 8-float unit index
        float4 a[4], b[4];
        #pragma unroll
        for (int c = 0; c < 4; ++c) {
            int j = jb + c * 1024;
            if (j < NUNITS) {
                int f4 = j * 2;
                if (f4 < NU4) { a[c] = uf4[f4];       b[c] = uf4[f4 + 1]; }
                else          { a[c] = if4[f4 - NU4]; b[c] = if4[f4 - NU4 + 1]; }
            }
        }
        #pragma unroll
        for (int c = 0; c < 4; ++c) {
            int j = jb + c * 1024;
            if (j < NUNITS) {
                uint2 pa = pack4(a[c]), pb = pack4(b[c]);
                *reinterpret_cast<uint4*>(F0 + (size_t)j * 8) =
                    make_uint4(pa.x, pa.y, pb.x, pb.y);
            }
        }
    } else {
        // ---- compact flags -> row list ----
        int idx = ((bid - NPART - CVB) * 1024 + t) * 4;
        if (idx >= NTOT) return;
        int4 f = *reinterpret_cast<const int4*>(flags + idx);
        int loc[4]; int k = 0;
        if (f.x) loc[k++] = idx;
        if (f.y) loc[k++] = idx + 1;
        if (f.z) loc[k++] = idx + 2;
        if (f.w) loc[k++] = idx + 3;
        if (k) {
            int base = atomicAdd(count, k);
            for (int m = 0; m < k; ++m) list[base + m] = loc[m];
        }
    }
}

// ---------------- agg core: branchless masked rounds, 8 lanes/row ----------------
// rp2 = {beg,cnt} -> single dwordx2 at chain head. Masked slots: e={0,0} ->
// row 0, w=0.0 -> exact +0, L1-hot.
__device__ __forceinline__ void agg_row8(int2 rc, int l8, int gb,
                                         const int2* __restrict__ entries,
                                         const unsigned short* __restrict__ src,
                                         float4& sL, float4& sH)
{
    int beg = rc.x, cnt = rc.y;
    float4 a0L = {0,0,0,0}, a0H = {0,0,0,0}, a1L = {0,0,0,0}, a1H = {0,0,0,0};
    for (int base = 0; base < cnt; base += 8) {
        int2 e = make_int2(0, 0);
        if (base + l8 < cnt) e = entries[beg + base + l8];
        int   c[8];
        float wv[8];
        #pragma unroll
        for (int k = 0; k < 8; ++k) {
            c[k]  = __shfl(e.x, gb + k);
            wv[k] = __int_as_float(__shfl(e.y, gb + k));
        }
        uint4 v[8];
        #pragma unroll
        for (int k = 0; k < 8; ++k)
            v[k] = *reinterpret_cast<const uint4*>(
                src + (size_t)c[k] * DIM + l8 * 8);
        #pragma unroll
        for (int k = 0; k < 8; ++k) {
            if (k & 1) {
                fma4(a1L, make_uint2(v[k].x, v[k].y), wv[k]);
                fma4(a1H, make_uint2(v[k].z, v[k].w), wv[k]);
            } else {
                fma4(a0L, make_uint2(v[k].x, v[k].y), wv[k]);
                fma4(a0H, make_uint2(v[k].z, v[k].w), wv[k]);
            }
        }
    }
    sL.x = a0L.x + a1L.x; sL.y = a0L.y + a1L.y;
    sL.z = a0L.z + a1L.z; sL.w = a0L.w + a1L.w;
    sH.x = a0H.x + a1H.x; sH.y = a0H.y + a1H.y;
    sH.z = a0H.z + a1H.z; sH.w = a0H.w + a1H.w;
}

// ---------------- layer 1 (all rows, gather only) ----------------
__global__ void agg1_kernel(const int2* __restrict__ rp2,
                            const int2* __restrict__ entries,
                            const unsigned short* __restrict__ F0,
                            unsigned short* __restrict__ H1)
{
    int gid = blockIdx.x * 256 + threadIdx.x;
    int lane = gid & 63;
    int l8 = lane & 7;
    int gb = lane & 56;
    int row = gid >> 3;
    if (row >= NTOT) return;
    float4 sL, sH;
    agg_row8(rp2[row], l8, gb, entries, F0, sL, sH);
    uint2 pL = pack4(sL), pH = pack4(sH);
    *reinterpret_cast<uint4*>(H1 + (size_t)row * DIM + l8 * 8) =
        make_uint4(pL.x, pL.y, pH.x, pH.y);
}

// ---------------- layer 2 (listed rows only) + out += 0.25*H1 ----------------
__global__ void agg2_add1_kernel(const int2* __restrict__ rp2,
                                 const int2* __restrict__ entries,
                                 const unsigned short* __restrict__ H1,
                                 unsigned short* __restrict__ H2,
                                 const int* __restrict__ list,
                                 const int* __restrict__ count,
                                 const int* __restrict__ users,
                                 const int* __restrict__ pos,
                                 const int* __restrict__ neg,
                                 float* __restrict__ out)
{
    int bid = blockIdx.x;
    if (bid < AB8) {
        int gid = bid * 256 + threadIdx.x;
        int lane = gid & 63;
        int l8 = lane & 7;
        int gb = lane & 56;
        int idx = gid >> 3;
        int n = *count;
        if (idx >= n) return;
        int row = list[idx];
        float4 sL, sH;
        agg_row8(rp2[row], l8, gb, entries, H1, sL, sH);
        uint2 pL = pack4(sL), pH = pack4(sH);
        *reinterpret_cast<uint4*>(H2 + (size_t)row * DIM + l8 * 8) =
            make_uint4(pL.x, pL.y, pH.x, pH.y);
    } else {
        // out += 0.25 * H1[bucket], 8 floats/thread (matches OB = NOUT*8/256)
        int idx = (bid - AB8) * 256 + threadIdx.x;   // [0, NOUT*8)
        int row = idx >> 3;
        if (row >= NOUT) return;
        int d8 = (idx & 7) << 3;
        int bucket = out_bucket(row, users, pos, neg);
        uint4 v = *reinterpret_cast<const uint4*>(H1 + (size_t)bucket * DIM + d8);
        float* op = out + (size_t)row * DIM + d8;
        float4 o0 = *reinterpret_cast<const float4*>(op);
        float4 o1 = *reinterpret_cast<const float4*>(op + 4);
        o0.x += 0.25f * __uint_as_float(v.x << 16);
        o0.y += 0.25f * __uint_as_float(v.x & 0xffff0000u);
        o0.z += 0.25f * __uint_as_float(v.y << 16);
        o0.w += 0.25f * __uint_as_float(v.y & 0xffff0000u);
        o1.x += 0.25f * __uint_as_float(v.z << 16);
        o1.y += 0.25f * __uint_as_float(v.z & 0xffff0000u);
        o1.z += 0.25f * __uint_as_float(v.w << 16);
        o1.w += 0.25f * __uint_as_float(v.w & 0xffff0000u);
        *reinterpret_cast<float4*>(op) = o0;
        *reinterpret_cast<float4*>(op + 4) = o1;
    }
}

// ---------------- layer 3 at output rows, H2 add fused IN-THREAD ----------------
__global__ void aggout_add2_kernel(const int2* __restrict__ rp2,
                                   const int2* __restrict__ entries,
                                   const unsigned short* __restrict__ H2,
                                   const int* __restrict__ users,
                                   const int* __restrict__ pos,
                                   const int* __restrict__ neg,
                                   float* __restrict__ out)
{
    int gid = blockIdx.x * 256 + threadIdx.x;
    int lane = gid & 63;
    int l8 = lane & 7;
    int gb = lane & 56;
    int orow = gid >> 3;
    if (orow >= NOUT) return;
    int bucket = out_bucket(orow, users, pos, neg);
    float4 sL, sH;
    agg_row8(rp2[bucket], l8, gb, entries, H2, sL, sH);
    uint4 v = *reinterpret_cast<const uint4*>(H2 + (size_t)bucket * DIM + l8 * 8);
    sL.x += __uint_as_float(v.x << 16);
    sL.y += __uint_as_float(v.x & 0xffff0000u);
    sL.z += __uint_as_float(v.y << 16);
    sL.w += __uint_as_float(v.y & 0xffff0000u);
    sH.x += __uint_as_float(v.z << 16);
    sH.y += __uint_as_float(v.z & 0xffff0000u);
    sH.z += __uint_as_float(v.w << 16);
    sH.w += __uint_as_float(v.w & 0xffff0000u);
    float* op = out + (size_t)orow * DIM + l8 * 8;
    float4 o0 = *reinterpret_cast<const float4*>(op);
    float4 o1 = *reinterpret_cast<const float4*>(op + 4);
    o0.x += 0.25f * sL.x; o0.y += 0.25f * sL.y;
    o0.z += 0.25f * sL.z; o0.w += 0.25f * sL.w;
    o1.x += 0.25f * sH.x; o1.y += 0.25f * sH.y;
    o1.z += 0.25f * sH.z; o1.w += 0.25f * sH.w;
    *reinterpret_cast<float4*>(op) = o0;
    *reinterpret_cast<float4*>(op + 4) = o1;
}

extern "C" void kernel_launch(void* const* d_in, const int* in_sizes, int n_in,
                              void* d_out, int out_size, void* d_ws, size_t ws_size,
                              hipStream_t stream)
{
    const float* user_feat = (const float*)d_in[0];
    const float* item_feat = (const float*)d_in[1];
    const int*   eu        = (const int*)d_in[2];
    const int*   ei        = (const int*)d_in[3];
    const float* norm      = (const float*)d_in[4];
    const int*   users     = (const int*)d_in[5];
    const int*   pos       = (const int*)d_in[6];
    const int*   neg       = (const int*)d_in[7];
    float* out = (float*)d_out;

    auto align256 = [](size_t x) { return (x + 255) & ~(size_t)255; };
    const size_t hBytes = (size_t)NTOT * DIM * sizeof(unsigned short);  // 38.4 MB
    const size_t pBytes = (size_t)NPART * CAP * 8;                      // 26.4 MB

    char* p = (char*)d_ws;
    unsigned short* F0 = (unsigned short*)p; p += align256(hBytes);
    unsigned short* H1 = (unsigned short*)p; p += align256(hBytes);
    unsigned short* H2 = (unsigned short*)p; p += align256(hBytes);
    // memset region: gcur(512 pad) | flags(NTOT) | count(16 pad) | isOut(NTOT B)
    const size_t zBytes = (size_t)(512 + NTOT + 16) * 4 + NTOT;
    int* gcur = (int*)p;
    int* flags = gcur + 512;
    int* count = flags + NTOT;
    unsigned char* isOut = (unsigned char*)(count + 16);
    p += align256(zBytes);
    int2* rp2      = (int2*)p;  p += align256((size_t)NTOT * 8);
    uint2* partBuf = (uint2*)p; p += align256(pBytes);
    int*  list     = (int*)p;   p += align256((size_t)NTOT * 4);
    int2* entries  = (int2*)p;  p += align256(pBytes);
    // total ~175 MB

    hipMemsetAsync(gcur, 0, zBytes, stream);

    // P: isOut bitmap + flags[bucket] + out_h0
    prep_kernel<<<PRB + PHB, 1024, 0, stream>>>(
        users, pos, neg, user_feat, item_feat, isOut, flags, out);

    // B: partition scatter + edge flags — ALONE (no concurrent stream)
    scatter_kernel<<<HA, 256, 0, stream>>>(
        eu, ei, norm, gcur, partBuf, isOut, flags);

    // M: csr || convert || compact (wide 1024-thr launch, wave-scan CSR)
    mid_kernel<<<NPART + CVB + CPB, 1024, 0, stream>>>(
        gcur, partBuf, rp2, entries,
        (const float4*)user_feat, (const float4*)item_feat, F0,
        flags, list, count);

    // layer 1 (all rows, gather only)
    agg1_kernel<<<AB8, 256, 0, stream>>>(rp2, entries, F0, H1);

    // layer 2 (listed rows) + out += 0.25*H1
    agg2_add1_kernel<<<AB8 + OB, 256, 0, stream>>>(
        rp2, entries, H1, H2, list, count, users, pos, neg, out);

    // layer 3 at output rows with in-thread H2 add
    aggout_add2_kernel<<<NOUT / 32, 256, 0, stream>>>(
        rp2, entries, H2, users, pos, neg, out);
}

// Round 15
// 260.905 us; speedup vs baseline: 1.1330x; 1.0284x over previous
//
#include <hip/hip_runtime.h>

// LightGCN propagation, CSR-gather, bf16 intermediates, unified row space.
// R24 (from R23 cooperative-launch FAILED silently; best = R18/R22 @267us):
//  - Cooperative fusion abandoned (launch failed under harness, no error
//    visibility). Same goal via ordinary launches: 7 -> 6 dispatches.
//  - compact/list/count DELETED: agg2 sweeps all rows flag-gated
//    (same gather work, ordered access, no list indirection).
//  - prep/isOut DELETED: flags via R17-verified agg1-tail CSR walk;
//    out_h0 + flags-zeroing moved into mid (read-streams, safe there —
//    only scatter's partBuf writes forbid co-tenants).
//  - Chain: memset(gcur 2KB) -> scatter -> mid{csr||conv||h0||zeroflags}
//    -> agg1+flag -> agg2(gated)+add1 -> aggout.

#define N_USERS 200000
#define N_ITEMS 100000
#define N_EDGES 1000000
#define DIM 64
#define BATCH 8192
#define NTOT (N_USERS + N_ITEMS)          // 300000 rows
#define NOUT (3 * BATCH)                  // 24576 output rows
#define NPART 293                         // ceil(NTOT / 1024)
#define PLOCAL 1024
#define CAP 11264                         // per-partition record capacity

#define HA 489                            // scatter blocks: 8 edges/thread
#define NUNITS (NTOT * DIM / 8)           // 2.4M 8-float convert units
#define OB (NOUT * 8 / 256)               // 768 add1 blocks (8 floats/thread)
#define AB8 (NTOT / 32)                   // 9375 agg blocks (32 rows/block)
#define FB ((NOUT + 255) / 256)           // 96 flag-walk blocks
#define CVB ((NUNITS + 4095) / 4096)      // 586 convert blocks (1024thr)
#define HB0 (NOUT * 8 / 1024)             // 192 out_h0 blocks (1024thr)
#define ZFB ((NTOT / 4 + 1023) / 1024)    // 74 zero-flags blocks (1024thr)

// ---------- bf16 helpers ----------
__device__ __forceinline__ unsigned f2bf(float f) {   // round-to-nearest-even
    unsigned u = __float_as_uint(f);
    return (u + 0x7fffu + ((u >> 16) & 1u)) >> 16;
}
__device__ __forceinline__ uint2 pack4(float4 v) {
    uint2 o;
    o.x = f2bf(v.x) | (f2bf(v.y) << 16);
    o.y = f2bf(v.z) | (f2bf(v.w) << 16);
    return o;
}
__device__ __forceinline__ void fma4(float4& a, uint2 v, float w) {
    a.x += __uint_as_float(v.x << 16) * w;
    a.y += __uint_as_float(v.x & 0xffff0000u) * w;
    a.z += __uint_as_float(v.y << 16) * w;
    a.w += __uint_as_float(v.y & 0xffff0000u) * w;
}
__device__ __forceinline__ int out_bucket(int orow, const int* users,
                                          const int* pos, const int* neg) {
    int seg = orow >> 13;
    int b = orow & (BATCH - 1);
    if (seg == 0) return users[b];
    if (seg == 1) return N_USERS + pos[b];
    return N_USERS + neg[b];
}

// ---------------- B: partition scatter (ALONE) ----------------
// record meta = (bucket & 1023) | (col << 10);  col < 2^19, total 29 bits.
// gcur[p] is ZERO-based (memset); record address = p*CAP + cursor.
__global__ void __launch_bounds__(256)
scatter_kernel(const int* __restrict__ eu,
               const int* __restrict__ ei,
               const float* __restrict__ w,
               int* __restrict__ gcur,
               uint2* __restrict__ partBuf)
{
    __shared__ int lh[NPART];
    __shared__ int lcur[NPART];
    int bid = blockIdx.x, t = threadIdx.x;
    for (int k = t; k < NPART; k += 256) lh[k] = 0;
    __syncthreads();
    int e0 = (bid * 256 + t) * 8;
    bool act = e0 < N_EDGES;
    int4 u0, u1, i0, i1;
    if (act) {
        u0 = *reinterpret_cast<const int4*>(eu + e0);
        u1 = *reinterpret_cast<const int4*>(eu + e0 + 4);
        i0 = *reinterpret_cast<const int4*>(ei + e0);
        i1 = *reinterpret_cast<const int4*>(ei + e0 + 4);
        atomicAdd(&lh[u0.x >> 10], 1);
        atomicAdd(&lh[u0.y >> 10], 1);
        atomicAdd(&lh[u0.z >> 10], 1);
        atomicAdd(&lh[u0.w >> 10], 1);
        atomicAdd(&lh[u1.x >> 10], 1);
        atomicAdd(&lh[u1.y >> 10], 1);
        atomicAdd(&lh[u1.z >> 10], 1);
        atomicAdd(&lh[u1.w >> 10], 1);
        atomicAdd(&lh[(N_USERS + i0.x) >> 10], 1);
        atomicAdd(&lh[(N_USERS + i0.y) >> 10], 1);
        atomicAdd(&lh[(N_USERS + i0.z) >> 10], 1);
        atomicAdd(&lh[(N_USERS + i0.w) >> 10], 1);
        atomicAdd(&lh[(N_USERS + i1.x) >> 10], 1);
        atomicAdd(&lh[(N_USERS + i1.y) >> 10], 1);
        atomicAdd(&lh[(N_USERS + i1.z) >> 10], 1);
        atomicAdd(&lh[(N_USERS + i1.w) >> 10], 1);
    }
    __syncthreads();
    // reserve: one returning atomic per (block, nonempty partition)
    for (int k = t; k < NPART; k += 256) {
        int v = lh[k];
        lcur[k] = v ? atomicAdd(&gcur[k], v) : 0;
    }
    __syncthreads();
    if (act) {
        float4 wa = *reinterpret_cast<const float4*>(w + e0);
        float4 wb = *reinterpret_cast<const float4*>(w + e0 + 4);
        int us[8] = {u0.x, u0.y, u0.z, u0.w, u1.x, u1.y, u1.z, u1.w};
        int is[8] = {i0.x, i0.y, i0.z, i0.w, i1.x, i1.y, i1.z, i1.w};
        float ws[8] = {wa.x, wa.y, wa.z, wa.w, wb.x, wb.y, wb.z, wb.w};
        #pragma unroll
        for (int j = 0; j < 8; ++j) {
            int bu = us[j];
            int bi = N_USERS + is[j];
            unsigned wbits = __float_as_uint(ws[j]);
            int pu = bu >> 10, pi = bi >> 10;
            int su = atomicAdd(&lcur[pu], 1);      // LDS cursor
            partBuf[(size_t)pu * CAP + su] =
                make_uint2((unsigned)(bu & 1023) | ((unsigned)bi << 10), wbits);
            int si = atomicAdd(&lcur[pi], 1);      // LDS cursor
            partBuf[(size_t)pi * CAP + si] =
                make_uint2((unsigned)(bi & 1023) | ((unsigned)bu << 10), wbits);
        }
    }
}

// ---------------- M: csr | convert | out_h0 | zero-flags (1024thr) ----------------
__global__ void __launch_bounds__(1024)
mid_kernel(const int* __restrict__ gcur,
           const uint2* __restrict__ partBuf,
           int2* __restrict__ rp2,
           int2* __restrict__ entries,
           const float4* __restrict__ uf4,
           const float4* __restrict__ if4,
           unsigned short* __restrict__ F0,
           const float* __restrict__ u_feat,
           const float* __restrict__ i_feat,
           const int* __restrict__ users,
           const int* __restrict__ pos,
           const int* __restrict__ neg,
           float* __restrict__ out,
           int* __restrict__ flags)
{
    int bid = blockIdx.x, t = threadIdx.x;
    if (bid < NPART) {
        // ---- per-partition CSR build, wave-scan (2 barriers) [R22] ----
        __shared__ int h[PLOCAL];
        __shared__ int cur[PLOCAL];
        __shared__ int wsum[16];
        int p = bid;
        int base = p * CAP;
        int end = base + gcur[p];
        h[t] = 0;
        __syncthreads();
        for (int r = base + t; r < end; r += 1024)
            atomicAdd(&h[partBuf[r].x & 1023], 1);
        __syncthreads();
        int v = h[t];
        int s = v;
        #pragma unroll
        for (int off = 1; off < 64; off <<= 1) {
            int x = __shfl_up(s, off, 64);
            if ((t & 63) >= off) s += x;
        }
        if ((t & 63) == 63) wsum[t >> 6] = s;
        __syncthreads();
        if (t < 16) {
            int ws = wsum[t];
            int acc = ws;
            #pragma unroll
            for (int off = 1; off < 16; off <<= 1) {
                int x = __shfl_up(acc, off, 64);
                if (t >= off) acc += x;
            }
            wsum[t] = acc - ws;                      // exclusive wave offset
        }
        __syncthreads();
        int excl = (s - v) + wsum[t >> 6];           // exclusive prefix
        int c0 = base + excl;
        cur[t] = c0;
        int gb = p * PLOCAL + t;
        if (gb < NTOT) rp2[gb] = make_int2(c0, v);
        __syncthreads();
        for (int r = base + t; r < end; r += 1024) {
            uint2 rec = partBuf[r];
            int slot = atomicAdd(&cur[rec.x & 1023], 1);   // LDS
            entries[slot] = make_int2((int)(rec.x >> 10), (int)rec.y);
        }
    } else if (bid < NPART + CVB) {
        // ---- f32 -> bf16 convert, 32 floats/thread, 8 loads in flight ----
        const int NU4 = N_USERS * DIM / 4;           // 3.2M float4s (user side)
        int jb = (bid - NPART) * 4096 + t;           // 8-float unit index
        float4 a[4], b[4];
        #pragma unroll
        for (int c = 0; c < 4; ++c) {
            int j = jb + c * 1024;
            if (j < NUNITS) {
                int f4 = j * 2;
                if (f4 < NU4) { a[c] = uf4[f4];       b[c] = uf4[f4 + 1]; }
                else          { a[c] = if4[f4 - NU4]; b[c] = if4[f4 - NU4 + 1]; }
            }
        }
        #pragma unroll
        for (int c = 0; c < 4; ++c) {
            int j = jb + c * 1024;
            if (j < NUNITS) {
                uint2 pa = pack4(a[c]), pb = pack4(b[c]);
                *reinterpret_cast<uint4*>(F0 + (size_t)j * 8) =
                    make_uint4(pa.x, pa.y, pb.x, pb.y);
            }
        }
    } else if (bid < NPART + CVB + HB0) {
        // ---- out = 0.25 * h0 at gathered rows, 8 floats/thread ----
        int idx = (bid - NPART - CVB) * 1024 + t;    // [0, NOUT*8) exactly
        int row = idx >> 3;
        int d8 = (idx & 7) << 3;
        int seg = row >> 13;
        int b = row & (BATCH - 1);
        const float* src;
        if (seg == 0)      src = u_feat + (size_t)users[b] * DIM;
        else if (seg == 1) src = i_feat + (size_t)pos[b]   * DIM;
        else               src = i_feat + (size_t)neg[b]   * DIM;
        float4 v0 = *reinterpret_cast<const float4*>(src + d8);
        float4 v1 = *reinterpret_cast<const float4*>(src + d8 + 4);
        v0.x *= 0.25f; v0.y *= 0.25f; v0.z *= 0.25f; v0.w *= 0.25f;
        v1.x *= 0.25f; v1.y *= 0.25f; v1.z *= 0.25f; v1.w *= 0.25f;
        float* op = out + (size_t)row * DIM + d8;
        *reinterpret_cast<float4*>(op) = v0;
        *reinterpret_cast<float4*>(op + 4) = v1;
    } else {
        // ---- zero flags (written next launch by agg1's flag walk) ----
        int i4 = (bid - NPART - CVB - HB0) * 1024 + t;
        if (i4 < NTOT / 4)
            reinterpret_cast<int4*>(flags)[i4] = make_int4(0, 0, 0, 0);
    }
}

// ---------------- agg core: branchless masked rounds, 8 lanes/row ----------------
__device__ __forceinline__ void agg_row8(int2 rc, int l8, int gb,
                                         const int2* __restrict__ entries,
                                         const unsigned short* __restrict__ src,
                                         float4& sL, float4& sH)
{
    int beg = rc.x, cnt = rc.y;
    float4 a0L = {0,0,0,0}, a0H = {0,0,0,0}, a1L = {0,0,0,0}, a1H = {0,0,0,0};
    for (int base = 0; base < cnt; base += 8) {
        int2 e = make_int2(0, 0);
        if (base + l8 < cnt) e = entries[beg + base + l8];
        int   c[8];
        float wv[8];
        #pragma unroll
        for (int k = 0; k < 8; ++k) {
            c[k]  = __shfl(e.x, gb + k);
            wv[k] = __int_as_float(__shfl(e.y, gb + k));
        }
        uint4 v[8];
        #pragma unroll
        for (int k = 0; k < 8; ++k)
            v[k] = *reinterpret_cast<const uint4*>(
                src + (size_t)c[k] * DIM + l8 * 8);
        #pragma unroll
        for (int k = 0; k < 8; ++k) {
            if (k & 1) {
                fma4(a1L, make_uint2(v[k].x, v[k].y), wv[k]);
                fma4(a1H, make_uint2(v[k].z, v[k].w), wv[k]);
            } else {
                fma4(a0L, make_uint2(v[k].x, v[k].y), wv[k]);
                fma4(a0H, make_uint2(v[k].z, v[k].w), wv[k]);
            }
        }
    }
    sL.x = a0L.x + a1L.x; sL.y = a0L.y + a1L.y;
    sL.z = a0L.z + a1L.z; sL.w = a0L.w + a1L.w;
    sH.x = a0H.x + a1H.x; sH.y = a0H.y + a1H.y;
    sH.z = a0H.z + a1H.z; sH.w = a0H.w + a1H.w;
}

// ---------------- layer 1 (all rows) + flag walk (R17 pattern) ----------------
__global__ void agg1_flag_kernel(const int2* __restrict__ rp2,
                                 const int2* __restrict__ entries,
                                 const unsigned short* __restrict__ F0,
                                 unsigned short* __restrict__ H1,
                                 const int* __restrict__ users,
                                 const int* __restrict__ pos,
                                 const int* __restrict__ neg,
                                 int* __restrict__ flags)
{
    int bid = blockIdx.x;
    if (bid < AB8) {
        int gid = bid * 256 + threadIdx.x;
        int lane = gid & 63;
        int l8 = lane & 7;
        int gb = lane & 56;
        int row = gid >> 3;
        if (row >= NTOT) return;
        float4 sL, sH;
        agg_row8(rp2[row], l8, gb, entries, F0, sL, sH);
        uint2 pL = pack4(sL), pH = pack4(sH);
        *reinterpret_cast<uint4*>(H1 + (size_t)row * DIM + l8 * 8) =
            make_uint4(pL.x, pL.y, pH.x, pH.y);
    } else {
        int t = (bid - AB8) * 256 + threadIdx.x;
        if (t >= NOUT) return;
        int bucket = out_bucket(t, users, pos, neg);
        flags[bucket] = 1;
        int2 rc = rp2[bucket];
        for (int k = rc.x; k < rc.x + rc.y; ++k)
            flags[entries[k].x] = 1;
    }
}

// ---------------- layer 2 (flag-gated full sweep) + out += 0.25*H1 ----------------
__global__ void agg2_add1_kernel(const int2* __restrict__ rp2,
                                 const int2* __restrict__ entries,
                                 const unsigned short* __restrict__ H1,
                                 unsigned short* __restrict__ H2,
                                 const int* __restrict__ flags,
                                 const int* __restrict__ users,
                                 const int* __restrict__ pos,
                                 const int* __restrict__ neg,
                                 float* __restrict__ out)
{
    int bid = blockIdx.x;
    if (bid < AB8) {
        int gid = bid * 256 + threadIdx.x;
        int lane = gid & 63;
        int l8 = lane & 7;
        int gb = lane & 56;
        int row = gid >> 3;
        if (row >= NTOT) return;
        if (!flags[row]) return;                       // gated: H2 not needed
        float4 sL, sH;
        agg_row8(rp2[row], l8, gb, entries, H1, sL, sH);
        uint2 pL = pack4(sL), pH = pack4(sH);
        *reinterpret_cast<uint4*>(H2 + (size_t)row * DIM + l8 * 8) =
            make_uint4(pL.x, pL.y, pH.x, pH.y);
    } else {
        // out += 0.25 * H1[bucket], 8 floats/thread (matches OB = NOUT*8/256)
        int idx = (bid - AB8) * 256 + threadIdx.x;     // [0, NOUT*8)
        int row = idx >> 3;
        if (row >= NOUT) return;
        int d8 = (idx & 7) << 3;
        int bucket = out_bucket(row, users, pos, neg);
        uint4 v = *reinterpret_cast<const uint4*>(H1 + (size_t)bucket * DIM + d8);
        float* op = out + (size_t)row * DIM + d8;
        float4 o0 = *reinterpret_cast<const float4*>(op);
        float4 o1 = *reinterpret_cast<const float4*>(op + 4);
        o0.x += 0.25f * __uint_as_float(v.x << 16);
        o0.y += 0.25f * __uint_as_float(v.x & 0xffff0000u);
        o0.z += 0.25f * __uint_as_float(v.y << 16);
        o0.w += 0.25f * __uint_as_float(v.y & 0xffff0000u);
        o1.x += 0.25f * __uint_as_float(v.z << 16);
        o1.y += 0.25f * __uint_as_float(v.z & 0xffff0000u);
        o1.z += 0.25f * __uint_as_float(v.w << 16);
        o1.w += 0.25f * __uint_as_float(v.w & 0xffff0000u);
        *reinterpret_cast<float4*>(op) = o0;
        *reinterpret_cast<float4*>(op + 4) = o1;
    }
}

// ---------------- layer 3 at output rows, H2 add fused IN-THREAD ----------------
__global__ void aggout_add2_kernel(const int2* __restrict__ rp2,
                                   const int2* __restrict__ entries,
                                   const unsigned short* __restrict__ H2,
                                   const int* __restrict__ users,
                                   const int* __restrict__ pos,
                                   const int* __restrict__ neg,
                                   float* __restrict__ out)
{
    int gid = blockIdx.x * 256 + threadIdx.x;
    int lane = gid & 63;
    int l8 = lane & 7;
    int gb = lane & 56;
    int orow = gid >> 3;
    if (orow >= NOUT) return;
    int bucket = out_bucket(orow, users, pos, neg);
    float4 sL, sH;
    agg_row8(rp2[bucket], l8, gb, entries, H2, sL, sH);
    uint4 v = *reinterpret_cast<const uint4*>(H2 + (size_t)bucket * DIM + l8 * 8);
    sL.x += __uint_as_float(v.x << 16);
    sL.y += __uint_as_float(v.x & 0xffff0000u);
    sL.z += __uint_as_float(v.y << 16);
    sL.w += __uint_as_float(v.y & 0xffff0000u);
    sH.x += __uint_as_float(v.z << 16);
    sH.y += __uint_as_float(v.z & 0xffff0000u);
    sH.z += __uint_as_float(v.w << 16);
    sH.w += __uint_as_float(v.w & 0xffff0000u);
    float* op = out + (size_t)orow * DIM + l8 * 8;
    float4 o0 = *reinterpret_cast<const float4*>(op);
    float4 o1 = *reinterpret_cast<const float4*>(op + 4);
    o0.x += 0.25f * sL.x; o0.y += 0.25f * sL.y;
    o0.z += 0.25f * sL.z; o0.w += 0.25f * sL.w;
    o1.x += 0.25f * sH.x; o1.y += 0.25f * sH.y;
    o1.z += 0.25f * sH.z; o1.w += 0.25f * sH.w;
    *reinterpret_cast<float4*>(op) = o0;
    *reinterpret_cast<float4*>(op + 4) = o1;
}

extern "C" void kernel_launch(void* const* d_in, const int* in_sizes, int n_in,
                              void* d_out, int out_size, void* d_ws, size_t ws_size,
                              hipStream_t stream)
{
    const float* user_feat = (const float*)d_in[0];
    const float* item_feat = (const float*)d_in[1];
    const int*   eu        = (const int*)d_in[2];
    const int*   ei        = (const int*)d_in[3];
    const float* norm      = (const float*)d_in[4];
    const int*   users     = (const int*)d_in[5];
    const int*   pos       = (const int*)d_in[6];
    const int*   neg       = (const int*)d_in[7];
    float* out = (float*)d_out;

    auto align256 = [](size_t x) { return (x + 255) & ~(size_t)255; };
    const size_t hBytes = (size_t)NTOT * DIM * sizeof(unsigned short);  // 38.4 MB
    const size_t pBytes = (size_t)NPART * CAP * 8;                      // 26.4 MB

    char* p = (char*)d_ws;
    unsigned short* F0 = (unsigned short*)p; p += align256(hBytes);
    unsigned short* H1 = (unsigned short*)p; p += align256(hBytes);
    unsigned short* H2 = (unsigned short*)p; p += align256(hBytes);
    int* gcur  = (int*)p;       p += align256(512 * 4);
    int* flags = (int*)p;       p += align256((size_t)NTOT * 4);
    int2* rp2      = (int2*)p;  p += align256((size_t)NTOT * 8);
    uint2* partBuf = (uint2*)p; p += align256(pBytes);
    int2* entries  = (int2*)p;  p += align256(pBytes);
    // total ~175 MB

    hipMemsetAsync(gcur, 0, 512 * 4, stream);

    // B: partition scatter — ALONE (no concurrent stream near partBuf writes)
    scatter_kernel<<<HA, 256, 0, stream>>>(eu, ei, norm, gcur, partBuf);

    // M: csr || convert || out_h0 || zero-flags (wide 1024-thr launch)
    mid_kernel<<<NPART + CVB + HB0 + ZFB, 1024, 0, stream>>>(
        gcur, partBuf, rp2, entries,
        (const float4*)user_feat, (const float4*)item_feat, F0,
        user_feat, item_feat, users, pos, neg, out, flags);

    // layer 1 (all rows) + flag walk
    agg1_flag_kernel<<<AB8 + FB, 256, 0, stream>>>(
        rp2, entries, F0, H1, users, pos, neg, flags);

    // layer 2 (flag-gated sweep) + out += 0.25*H1
    agg2_add1_kernel<<<AB8 + OB, 256, 0, stream>>>(
        rp2, entries, H1, H2, flags, users, pos, neg, out);

    // layer 3 at output rows with in-thread H2 add
    aggout_add2_kernel<<<NOUT / 32, 256, 0, stream>>>(
        rp2, entries, H2, users, pos, neg, out);
}